// Round 22
// baseline (126.886 us; speedup 1.0000x reference)
//
#include <hip/hip_runtime.h>

#define HD 256
#define LN_EPS 1e-5f
#define DEG_EPS 1e-6f
#define CAP 64
#define C2 264

typedef __attribute__((ext_vector_type(8))) short short8;
typedef __attribute__((ext_vector_type(4))) short s16x4;
typedef __attribute__((ext_vector_type(4))) float f32x4;
typedef __attribute__((ext_vector_type(4))) int i32x4;

__device__ inline unsigned short f2bf(float f) {
    union { float f; unsigned int u; } v; v.f = f;
    unsigned int r = v.u + 0x7FFFu + ((v.u >> 16) & 1u);
    return (unsigned short)(r >> 16);
}

// Blocks [0,zb): zero counts. Blocks [zb, zb+256): W12 = W2[:, :256]@W1
// (fp32 accumulate -> bf16), bv = W2@b1, ucol = clue column of W2.
__global__ __launch_bounds__(256) void prep0_kernel(
    int* __restrict__ counts, int num_con,
    const float* __restrict__ msg_W, const float* __restrict__ msg_b,
    const float* __restrict__ upd_W,
    unsigned short* __restrict__ w12b, float* __restrict__ bv,
    float* __restrict__ ucol, int zb) {
    int b = blockIdx.x, tid = threadIdx.x;
    if (b < zb) {
        int i = (b * 256 + tid) * 4;
        if (i + 4 <= num_con) *(i32x4*)(counts + i) = (i32x4){0, 0, 0, 0};
        else for (; i < num_con; ++i) counts[i] = 0;
    } else {
        int j = b - zb, k = tid;
        float a0 = 0.f, a1 = 0.f, a2 = 0.f, a3 = 0.f, accb = 0.f;
#pragma unroll 2
        for (int m = 0; m < 256; m += 4) {
            float w0 = upd_W[j * 257 + m + 0];
            float w1 = upd_W[j * 257 + m + 1];
            float w2 = upd_W[j * 257 + m + 2];
            float w3 = upd_W[j * 257 + m + 3];
            a0 = fmaf(w0, msg_W[(m + 0) * 256 + k], a0);
            a1 = fmaf(w1, msg_W[(m + 1) * 256 + k], a1);
            a2 = fmaf(w2, msg_W[(m + 2) * 256 + k], a2);
            a3 = fmaf(w3, msg_W[(m + 3) * 256 + k], a3);
            accb = fmaf(w0, msg_b[m + 0], accb);
            accb = fmaf(w1, msg_b[m + 1], accb);
            accb = fmaf(w2, msg_b[m + 2], accb);
            accb = fmaf(w3, msg_b[m + 3], accb);
        }
        w12b[j * 256 + k] = f2bf((a0 + a1) + (a2 + a3));
        if (k == 0) { bv[j] = accb; ucol[j] = upd_W[j * 257 + 256]; }
    }
}

// Bucket edges by dst: counts[] = degree, eidx[d*CAP + p] = src ids.
__global__ __launch_bounds__(256) void fill_kernel(
    const int* __restrict__ src, const int* __restrict__ dst,
    int* __restrict__ counts, int* __restrict__ eidx, int E) {
    int e = blockIdx.x * 256 + threadIdx.x;
    if (e >= E) return;
    int d = dst[e];
    int p = atomicAdd(&counts[d], 1);
    if (p < CAP) eidx[d * CAP + p] = src[e];
}

// R7-measured gather (62us): one wave per constraint row, 4 rows per
// 256-thr block; reads fp32 x_var rows DIRECTLY (no cast pass), batch-4
// jam keeps 4 1KB-row loads in flight. Emits deg-scaled bf16 agg.
// 20 VGPR -> ~8 waves/SIMD; latency hidden by TLP.
__global__ __launch_bounds__(256) void gather_kernel(
    const float* __restrict__ x_var, const int* __restrict__ counts,
    const int* __restrict__ eidx, unsigned short* __restrict__ agg,
    int num_con) {
    int row  = blockIdx.x * 4 + (threadIdx.x >> 6);
    int lane = threadIdx.x & 63;
    if (row >= num_con) return;
    int cnt = counts[row];
    int cgo = min(cnt, CAP);
    int sid = (lane < cgo) ? eidx[row * CAP + lane] : 0;
    float a0 = 0.f, a1 = 0.f, a2 = 0.f, a3 = 0.f;
#pragma unroll 1
    for (int i = 0; i < cgo; i += 4) {
        int s0 = __shfl(sid, i, 64);
        int s1 = __shfl(sid, i + 1, 64);
        int s2 = __shfl(sid, i + 2, 64);
        int s3 = __shfl(sid, i + 3, 64);
        float4 v0 = *(const float4*)(x_var + (long)s0 * HD + lane * 4);
        float4 v1 = *(const float4*)(x_var + (long)s1 * HD + lane * 4);
        float4 v2 = *(const float4*)(x_var + (long)s2 * HD + lane * 4);
        float4 v3 = *(const float4*)(x_var + (long)s3 * HD + lane * 4);
        float w1 = (i + 1 < cgo) ? 1.f : 0.f;
        float w2 = (i + 2 < cgo) ? 1.f : 0.f;
        float w3 = (i + 3 < cgo) ? 1.f : 0.f;
        a0 += v0.x + v1.x * w1 + v2.x * w2 + v3.x * w3;
        a1 += v0.y + v1.y * w1 + v2.y * w2 + v3.y * w3;
        a2 += v0.z + v1.z * w1 + v2.z * w2 + v3.z * w3;
        a3 += v0.w + v1.w * w1 + v2.w * w2 + v3.w * w3;
    }
    float sc = 1.0f / ((float)cnt + DEG_EPS);
    s16x4 o;
    o[0] = (short)f2bf(a0 * sc); o[1] = (short)f2bf(a1 * sc);
    o[2] = (short)f2bf(a2 * sc); o[3] = (short)f2bf(a3 * sc);
    *(s16x4*)(agg + (long)row * HD + lane * 4) = o;
}

// Single fused GEMM (R13-verified):
// out = LN(relu(agg @ W12^T + tcoef*bv + ucol*clue + b2)) * ln_w + ln_b.
// 4 waves; wave w holds W12 rows [w*64,+64) in 128 VGPR. A-tile staged
// cooperatively in XOR-swizzled LDS once per tile. Grid-stride 16-row tiles.
__global__ __launch_bounds__(256) void gfinal_kernel(
    const unsigned short* __restrict__ agg, const int* __restrict__ counts,
    const float* __restrict__ clue,
    const unsigned short* __restrict__ w12b, const float* __restrict__ bv,
    const float* __restrict__ ucol, const float* __restrict__ upd_b,
    const float* __restrict__ ln_w, const float* __restrict__ ln_b,
    float* __restrict__ out, int num_con, int ntiles) {

    __shared__ unsigned short sA[16 * 256];   // 8 KB, XOR-swizzled rows
    __shared__ float sZ[2][16 * C2];
    const int tid = threadIdx.x, w = tid >> 6, lane = tid & 63;
    const int lr = lane & 15, lg = lane >> 4;

    short8 bfr[4][8];
#pragma unroll
    for (int jt = 0; jt < 4; ++jt)
#pragma unroll
        for (int ks = 0; ks < 8; ++ks)
            bfr[jt][ks] = *(const short8*)(w12b + (w * 64 + jt * 16 + lr) * HD + lg * 8 + ks * 32);
    float uc[4], b2[4], bvv[4];
#pragma unroll
    for (int jt = 0; jt < 4; ++jt) {
        uc[jt]  = ucol[w * 64 + jt * 16 + lr];
        b2[jt]  = upd_b[w * 64 + jt * 16 + lr];
        bvv[jt] = bv[w * 64 + jt * 16 + lr];
    }
    const int seg = tid & 15;
    f32x4 lw[4], lb[4];
#pragma unroll
    for (int k = 0; k < 4; ++k) {
        lw[k] = *(const f32x4*)(ln_w + seg * 16 + k * 4);
        lb[k] = *(const f32x4*)(ln_b + seg * 16 + k * 4);
    }
    const int srow = tid >> 4, scol = (tid & 15) * 16;

    int buf = 0;
#pragma unroll 1
    for (int rt = blockIdx.x; rt < ntiles; rt += gridDim.x) {
        int r0 = rt * 16;
        {
            int arc = min(r0 + srow, num_con - 1);
            const unsigned short* gp = agg + (long)arc * HD + scol;
            short8 v0 = *(const short8*)(gp);
            short8 v1 = *(const short8*)(gp + 8);
            int b0 = (srow * 512 + scol * 2) ^ ((srow & 7) << 4);
            int b1 = (srow * 512 + scol * 2 + 16) ^ ((srow & 7) << 4);
            *(short8*)((char*)sA + b0) = v0;
            *(short8*)((char*)sA + b1) = v1;
        }
        __syncthreads();

        short8 af[8];
#pragma unroll
        for (int ks = 0; ks < 8; ++ks) {
            int byte = (lr * 512 + (ks * 32 + lg * 8) * 2) ^ ((lr & 7) << 4);
            af[ks] = *(const short8*)((char*)sA + byte);
        }

        f32x4 acc[4] = {{0.f,0.f,0.f,0.f},{0.f,0.f,0.f,0.f},{0.f,0.f,0.f,0.f},{0.f,0.f,0.f,0.f}};
#pragma unroll
        for (int ks = 0; ks < 8; ++ks)
#pragma unroll
            for (int jt = 0; jt < 4; ++jt)
                acc[jt] = __builtin_amdgcn_mfma_f32_16x16x32_bf16(af[ks], bfr[jt][ks], acc[jt], 0, 0, 0);

        float cl[4], trow[4];
#pragma unroll
        for (int q = 0; q < 4; ++q) {
            int rr = min(r0 + lg * 4 + q, num_con - 1);
            cl[q] = clue[rr];
            float dvq = (float)counts[rr];
            trow[q] = dvq / (dvq + DEG_EPS);
        }
#pragma unroll
        for (int jt = 0; jt < 4; ++jt)
#pragma unroll
            for (int q = 0; q < 4; ++q) {
                float z = fmaxf(acc[jt][q] + trow[q] * bvv[jt] + uc[jt] * cl[q] + b2[jt], 0.0f);
                sZ[buf][(lg * 4 + q) * C2 + w * 64 + jt * 16 + lr] = z;
            }
        __syncthreads();
        {
            int row = tid >> 4;
            const float* zp = &sZ[buf][row * C2 + seg * 16];
            f32x4 z4[4];
            float s = 0.f, s2 = 0.f;
#pragma unroll
            for (int k = 0; k < 4; ++k) {
                z4[k] = *(const f32x4*)(zp + k * 4);
#pragma unroll
                for (int e = 0; e < 4; ++e) { s += z4[k][e]; s2 += z4[k][e] * z4[k][e]; }
            }
#pragma unroll
            for (int m = 1; m < 16; m <<= 1) {
                s  += __shfl_xor(s,  m, 64);
                s2 += __shfl_xor(s2, m, 64);
            }
            float mu = s * (1.0f / HD);
            float var = s2 * (1.0f / HD) - mu * mu;
            float rs = rsqrtf(var + LN_EPS);
            int grow = r0 + row;
            if (grow < num_con) {
                float* gp = out + (long)grow * HD + seg * 16;
#pragma unroll
                for (int k = 0; k < 4; ++k) {
                    f32x4 o;
#pragma unroll
                    for (int e = 0; e < 4; ++e)
                        o[e] = (z4[k][e] - mu) * rs * lw[k][e] + lb[k][e];
                    *(f32x4*)(gp + k * 4) = o;
                }
            }
        }
        buf ^= 1;
    }
}

extern "C" void kernel_launch(void* const* d_in, const int* in_sizes, int n_in,
                              void* d_out, int out_size, void* d_ws, size_t ws_size,
                              hipStream_t stream) {
    const float* x_var = (const float*)d_in[0];
    const int*   src   = (const int*)d_in[1];
    const int*   dst   = (const int*)d_in[2];
    const float* clue  = (const float*)d_in[3];
    // d_in[4] = num_con scalar (derived from out_size instead)
    const float* msg_W = (const float*)d_in[5];
    const float* msg_b = (const float*)d_in[6];
    const float* upd_W = (const float*)d_in[7];
    const float* upd_b = (const float*)d_in[8];
    const float* ln_w  = (const float*)d_in[9];
    const float* ln_b  = (const float*)d_in[10];

    int E = in_sizes[1];
    int num_con = out_size / HD;
    int ntiles = (num_con + 15) / 16;

    char* ws = (char*)d_ws;
    int* counts = (int*)ws;                               // num_con ints
    int* eidx   = (int*)(ws + (((size_t)num_con * 4 + 255) & ~(size_t)255));
    char* after = (char*)(eidx + (size_t)num_con * CAP);  // num_con*CAP ints
    size_t aoff = ((size_t)(after - ws) + 255) & ~(size_t)255;
    unsigned short* agg = (unsigned short*)(ws + aoff);   // num_con*256 bf16
    size_t woff = (aoff + (size_t)num_con * HD * 2 + 255) & ~(size_t)255;
    unsigned short* w12b = (unsigned short*)(ws + woff);  // 256*256 bf16
    float* bvp  = (float*)(w12b + 256 * 256);             // 256 fp32
    float* ucol = bvp + 256;                              // 256 fp32

    int zb = (num_con + 1023) / 1024;
    prep0_kernel<<<zb + 256, 256, 0, stream>>>(
        counts, num_con, msg_W, msg_b, upd_W, w12b, bvp, ucol, zb);

    fill_kernel<<<(E + 255) / 256, 256, 0, stream>>>(src, dst, counts, eidx, E);

    gather_kernel<<<(num_con + 3) / 4, 256, 0, stream>>>(
        x_var, counts, eidx, agg, num_con);

    gfinal_kernel<<<1024, 256, 0, stream>>>(
        agg, counts, clue, w12b, bvp, ucol, upd_b, ln_w, ln_b,
        (float*)d_out, num_con, ntiles);
}

// Round 23
// 105.732 us; speedup vs baseline: 1.2001x; 1.2001x over previous
//
#include <hip/hip_runtime.h>

#define HD 256
#define LN_EPS 1e-5f
#define DEG_EPS 1e-6f
#define CAP 64

typedef __attribute__((ext_vector_type(8))) short short8;
typedef __attribute__((ext_vector_type(4))) short s16x4;
typedef __attribute__((ext_vector_type(4))) float f32x4;
typedef __attribute__((ext_vector_type(4))) int i32x4;

__device__ inline unsigned short f2bf(float f) {
    union { float f; unsigned int u; } v; v.f = f;
    unsigned int r = v.u + 0x7FFFu + ((v.u >> 16) & 1u);
    return (unsigned short)(r >> 16);
}
__device__ inline float bf2f(unsigned short h) {
    union { unsigned int u; float f; } v; v.u = ((unsigned int)h) << 16;
    return v.f;
}
__device__ inline short8 cvt8(f32x4 u0, f32x4 u1) {
    short8 o;
    o[0] = (short)f2bf(u0[0]); o[1] = (short)f2bf(u0[1]);
    o[2] = (short)f2bf(u0[2]); o[3] = (short)f2bf(u0[3]);
    o[4] = (short)f2bf(u1[0]); o[5] = (short)f2bf(u1[1]);
    o[6] = (short)f2bf(u1[2]); o[7] = (short)f2bf(u1[3]);
    return o;
}

// Blocks [0,zb): zero counts. Blocks [zb, zb+256): W12 = W2[:, :256]@W1
// (fp32 accumulate -> bf16), bv = W2@b1, ucol = clue column of W2.
__global__ __launch_bounds__(256) void prep0_kernel(
    int* __restrict__ counts, int num_con,
    const float* __restrict__ msg_W, const float* __restrict__ msg_b,
    const float* __restrict__ upd_W,
    unsigned short* __restrict__ w12b, float* __restrict__ bv,
    float* __restrict__ ucol, int zb) {
    int b = blockIdx.x, tid = threadIdx.x;
    if (b < zb) {
        int i = (b * 256 + tid) * 4;
        if (i + 4 <= num_con) *(i32x4*)(counts + i) = (i32x4){0, 0, 0, 0};
        else for (; i < num_con; ++i) counts[i] = 0;
    } else {
        int j = b - zb, k = tid;
        float a0 = 0.f, a1 = 0.f, a2 = 0.f, a3 = 0.f, accb = 0.f;
#pragma unroll 2
        for (int m = 0; m < 256; m += 4) {
            float w0 = upd_W[j * 257 + m + 0];
            float w1 = upd_W[j * 257 + m + 1];
            float w2 = upd_W[j * 257 + m + 2];
            float w3 = upd_W[j * 257 + m + 3];
            a0 = fmaf(w0, msg_W[(m + 0) * 256 + k], a0);
            a1 = fmaf(w1, msg_W[(m + 1) * 256 + k], a1);
            a2 = fmaf(w2, msg_W[(m + 2) * 256 + k], a2);
            a3 = fmaf(w3, msg_W[(m + 3) * 256 + k], a3);
            accb = fmaf(w0, msg_b[m + 0], accb);
            accb = fmaf(w1, msg_b[m + 1], accb);
            accb = fmaf(w2, msg_b[m + 2], accb);
            accb = fmaf(w3, msg_b[m + 3], accb);
        }
        w12b[j * 256 + k] = f2bf((a0 + a1) + (a2 + a3));
        if (k == 0) { bv[j] = accb; ucol[j] = upd_W[j * 257 + 256]; }
    }
}

// Bucket edges by dst: counts[] = degree, eidx[d*CAP + p] = src ids.
__global__ __launch_bounds__(256) void fill_kernel(
    const int* __restrict__ src, const int* __restrict__ dst,
    int* __restrict__ counts, int* __restrict__ eidx, int E) {
    int e = blockIdx.x * 256 + threadIdx.x;
    if (e >= E) return;
    int d = dst[e];
    int p = atomicAdd(&counts[d], 1);
    if (p < CAP) eidx[d * CAP + p] = src[e];
}

// y = bf16(x @ W12^T), permuted layout col' = w*32+lr*2+jt <-> true col
// w*32+jt*16+lr. 512 thr = 8 waves, wave strip = 32 cols so the weight
// array is 64 VGPR and PROVABLY register-resident (R19's 64-col version
// reported VGPR=100 < its 128-reg weight array => compiler was reloading
// all weights from L2 inside every tile). Same staged-LDS + prefetch
// schedule as R19: LDS-write(t) -> barrier -> issue loads(t+1) -> compute.
__global__ __launch_bounds__(512) void ygemm_kernel(
    const float* __restrict__ x, const unsigned short* __restrict__ w12b,
    unsigned short* __restrict__ y, int n_var, int ntiles) {

    __shared__ unsigned short sA[2][16 * 256];   // 2 x 8 KB swizzled bf16 A
    const int tid = threadIdx.x, w = tid >> 6, lane = tid & 63;
    const int lr = lane & 15, lg = lane >> 4;

    // strip weights: rows w*32 + jt*16 + lr (jt=0,1) -> 64 VGPR
    short8 bfr[2][8];
#pragma unroll
    for (int jt = 0; jt < 2; ++jt)
#pragma unroll
        for (int ks = 0; ks < 8; ++ks)
            bfr[jt][ks] = *(const short8*)(w12b + (w * 32 + jt * 16 + lr) * HD + lg * 8 + ks * 32);

    // staging: 32 thr/row, 16B (8 fp32 -> 8 bf16) per thread
    const int srow = tid >> 5, scol = (tid & 31) * 8;    // col in floats/shorts
    const int sb = (srow * 512 + scol * 2) ^ ((srow & 7) << 4);

    int rt = blockIdx.x;
    f32x4 u0, u1;
    if (rt < ntiles) {
        int arc = min(rt * 16 + srow, n_var - 1);
        const f32x4* gp = (const f32x4*)(x + (long)arc * HD + scol);
        u0 = gp[0];
        u1 = gp[1];
    }

    int buf = 0;
#pragma unroll 1
    for (; rt < ntiles; ) {
        int r0 = rt * 16;
        // ---- write the prefetched (in-register) tile to LDS ----
        *(short8*)((char*)&sA[buf][0] + sb) = cvt8(u0, u1);

        // ---- barrier BEFORE issuing next loads (nothing in flight) ----
        __syncthreads();

        // ---- issue next tile's loads; in flight across compute ----
        int nrt = rt + gridDim.x;
        {
            int prt = min(nrt, ntiles - 1);
            int arc = min(prt * 16 + srow, n_var - 1);
            const f32x4* gp = (const f32x4*)(x + (long)arc * HD + scol);
            u0 = gp[0];
            u1 = gp[1];
        }

        short8 af[8];
#pragma unroll
        for (int ks = 0; ks < 8; ++ks) {
            int byte = (lr * 512 + (ks * 32 + lg * 8) * 2) ^ ((lr & 7) << 4);
            af[ks] = *(const short8*)((char*)&sA[buf][0] + byte);
        }

        f32x4 acc[2] = {{0.f,0.f,0.f,0.f},{0.f,0.f,0.f,0.f}};
#pragma unroll
        for (int ks = 0; ks < 8; ++ks)
#pragma unroll
            for (int jt = 0; jt < 2; ++jt)
                acc[jt] = __builtin_amdgcn_mfma_f32_16x16x32_bf16(af[ks], bfr[jt][ks], acc[jt], 0, 0, 0);

        // ---- permuted store: lane packs its 2 jt-values -> u32 ----
#pragma unroll
        for (int q = 0; q < 4; ++q) {
            int grow = r0 + lg * 4 + q;
            if (grow < n_var) {
                unsigned int pk = (unsigned int)f2bf(acc[0][q]) |
                                  (((unsigned int)f2bf(acc[1][q])) << 16);
                *(unsigned int*)(y + (long)grow * HD + w * 32 + lr * 2) = pk;
            }
        }
        buf ^= 1;
        rt = nrt;
    }
}

// Gather + epilogue. y permuted: col' holds true col
// tc = (col' & ~31) | ((col' & 1) << 4) | ((col' & 31) >> 1).
// Per-col params loaded at tc; LN sum is order-agnostic; stores at tc.
__global__ __launch_bounds__(256) void gatherln_kernel(
    const unsigned short* __restrict__ y, const int* __restrict__ counts,
    const int* __restrict__ eidx, const float* __restrict__ clue,
    const float* __restrict__ bv, const float* __restrict__ ucol,
    const float* __restrict__ upd_b,
    const float* __restrict__ ln_w, const float* __restrict__ ln_b,
    float* __restrict__ out, int num_con) {
    int row  = blockIdx.x * 4 + (threadIdx.x >> 6);
    int lane = threadIdx.x & 63;
    if (row >= num_con) return;
    int cnt = counts[row];
    int cgo = min(cnt, CAP);
    int sid = (lane < cgo) ? eidx[row * CAP + lane] : 0;
    float a0 = 0.f, a1 = 0.f, a2 = 0.f, a3 = 0.f;
#pragma unroll 1
    for (int i = 0; i < cgo; i += 8) {
        int s[8];
#pragma unroll
        for (int u = 0; u < 8; ++u) s[u] = __shfl(sid, i + u, 64);
        s16x4 v[8];
#pragma unroll
        for (int u = 0; u < 8; ++u)
            v[u] = *(const s16x4*)(y + (long)s[u] * HD + lane * 4);
#pragma unroll
        for (int u = 0; u < 8; ++u) {
            float wg = (i + u < cgo) ? 1.f : 0.f;
            a0 = fmaf(bf2f((unsigned short)v[u][0]), wg, a0);
            a1 = fmaf(bf2f((unsigned short)v[u][1]), wg, a1);
            a2 = fmaf(bf2f((unsigned short)v[u][2]), wg, a2);
            a3 = fmaf(bf2f((unsigned short)v[u][3]), wg, a3);
        }
    }
    float sc = 1.0f / ((float)cnt + DEG_EPS);
    float tc = (float)cnt * sc;
    float cl = clue[row];
    float z[4] = {a0, a1, a2, a3};
    int tcol[4];
    float s = 0.f, s2 = 0.f;
#pragma unroll
    for (int c = 0; c < 4; ++c) {
        int cc = lane * 4 + c;                                // permuted col'
        int t = (cc & ~31) | ((cc & 1) << 4) | ((cc & 31) >> 1); // true col
        tcol[c] = t;
        float zz = fmaxf(z[c] * sc + tc * bv[t] + cl * ucol[t] + upd_b[t], 0.0f);
        z[c] = zz;
        s += zz; s2 += zz * zz;
    }
#pragma unroll
    for (int m = 1; m < 64; m <<= 1) {
        s  += __shfl_xor(s,  m, 64);
        s2 += __shfl_xor(s2, m, 64);
    }
    float mu = s * (1.0f / HD);
    float var = s2 * (1.0f / HD) - mu * mu;
    float rs = rsqrtf(var + LN_EPS);
    float* gp = out + (long)row * HD;
#pragma unroll
    for (int c = 0; c < 4; ++c) {
        int t = tcol[c];
        gp[t] = (z[c] - mu) * rs * ln_w[t] + ln_b[t];
    }
}

extern "C" void kernel_launch(void* const* d_in, const int* in_sizes, int n_in,
                              void* d_out, int out_size, void* d_ws, size_t ws_size,
                              hipStream_t stream) {
    const float* x_var = (const float*)d_in[0];
    const int*   src   = (const int*)d_in[1];
    const int*   dst   = (const int*)d_in[2];
    const float* clue  = (const float*)d_in[3];
    // d_in[4] = num_con scalar (derived from out_size instead)
    const float* msg_W = (const float*)d_in[5];
    const float* msg_b = (const float*)d_in[6];
    const float* upd_W = (const float*)d_in[7];
    const float* upd_b = (const float*)d_in[8];
    const float* ln_w  = (const float*)d_in[9];
    const float* ln_b  = (const float*)d_in[10];

    int E = in_sizes[1];
    long n_x = in_sizes[0];
    int n_var = (int)(n_x / HD);
    int num_con = out_size / HD;
    int ntiles_v = (n_var + 15) / 16;

    char* ws = (char*)d_ws;
    int* counts = (int*)ws;                               // num_con ints
    int* eidx   = (int*)(ws + (((size_t)num_con * 4 + 255) & ~(size_t)255));
    char* after = (char*)(eidx + (size_t)num_con * CAP);  // num_con*CAP ints
    size_t yoff = ((size_t)(after - ws) + 255) & ~(size_t)255;
    unsigned short* yv = (unsigned short*)(ws + yoff);    // n_var*256 bf16 (permuted)
    size_t woff = (yoff + (size_t)n_var * HD * 2 + 255) & ~(size_t)255;
    unsigned short* w12b = (unsigned short*)(ws + woff);  // 256*256 bf16
    float* bvp  = (float*)(w12b + 256 * 256);             // 256 fp32
    float* ucol = bvp + 256;                              // 256 fp32

    int zb = (num_con + 1023) / 1024;
    prep0_kernel<<<zb + 256, 256, 0, stream>>>(
        counts, num_con, msg_W, msg_b, upd_W, w12b, bvp, ucol, zb);

    fill_kernel<<<(E + 255) / 256, 256, 0, stream>>>(src, dst, counts, eidx, E);

    ygemm_kernel<<<1024, 512, 0, stream>>>(x_var, w12b, yv, n_var, ntiles_v);

    gatherln_kernel<<<(num_con + 3) / 4, 256, 0, stream>>>(
        yv, counts, eidx, clue, bvp, ucol, upd_b, ln_w, ln_b,
        (float*)d_out, num_con);
}

// Round 25
// 103.410 us; speedup vs baseline: 1.2270x; 1.0225x over previous
//
#include <hip/hip_runtime.h>

#define HD 256
#define LN_EPS 1e-5f
#define DEG_EPS 1e-6f
#define CAP 64

typedef __attribute__((ext_vector_type(8))) short short8;
typedef __attribute__((ext_vector_type(4))) short s16x4;
typedef __attribute__((ext_vector_type(4))) float f32x4;
typedef __attribute__((ext_vector_type(4))) int i32x4;

__device__ inline unsigned short f2bf(float f) {
    union { float f; unsigned int u; } v; v.f = f;
    unsigned int r = v.u + 0x7FFFu + ((v.u >> 16) & 1u);
    return (unsigned short)(r >> 16);
}
__device__ inline float bf2f(unsigned short h) {
    union { unsigned int u; float f; } v; v.u = ((unsigned int)h) << 16;
    return v.f;
}
__device__ inline short8 cvt8(float4 u0, float4 u1) {
    short8 o;
    o[0] = (short)f2bf(u0.x); o[1] = (short)f2bf(u0.y);
    o[2] = (short)f2bf(u0.z); o[3] = (short)f2bf(u0.w);
    o[4] = (short)f2bf(u1.x); o[5] = (short)f2bf(u1.y);
    o[6] = (short)f2bf(u1.z); o[7] = (short)f2bf(u1.w);
    return o;
}

// Zero counts (tiny; 49 blocks).
__global__ __launch_bounds__(256) void zero_kernel(int* __restrict__ p, int n) {
    int i = (blockIdx.x * 256 + threadIdx.x) * 4;
    if (i + 4 <= n) {
        *(i32x4*)(p + i) = (i32x4){0, 0, 0, 0};
    } else {
        for (; i < n; ++i) p[i] = 0;
    }
}

// Fused independent prep: blocks [0,FB) bucket edges by dst (fill);
// blocks [FB,FB+256) compute W12 = W2[:, :256]@W1 (fp32 acc -> bf16),
// bv = W2@b1, ucol = clue column of W2. Both only require counts zeroed.
__global__ __launch_bounds__(256) void fillw12_kernel(
    const int* __restrict__ src, const int* __restrict__ dst,
    int* __restrict__ counts, int* __restrict__ eidx, int E, int FB,
    const float* __restrict__ msg_W, const float* __restrict__ msg_b,
    const float* __restrict__ upd_W,
    unsigned short* __restrict__ w12b, float* __restrict__ bv,
    float* __restrict__ ucol) {
    int b = blockIdx.x, tid = threadIdx.x;
    if (b < FB) {
        int e = b * 256 + tid;
        if (e < E) {
            int d = dst[e];
            int p = atomicAdd(&counts[d], 1);
            if (p < CAP) eidx[d * CAP + p] = src[e];
        }
    } else {
        int j = b - FB, k = tid;
        float a0 = 0.f, a1 = 0.f, a2 = 0.f, a3 = 0.f, accb = 0.f;
#pragma unroll 2
        for (int m = 0; m < 256; m += 4) {
            float w0 = upd_W[j * 257 + m + 0];
            float w1 = upd_W[j * 257 + m + 1];
            float w2 = upd_W[j * 257 + m + 2];
            float w3 = upd_W[j * 257 + m + 3];
            a0 = fmaf(w0, msg_W[(m + 0) * 256 + k], a0);
            a1 = fmaf(w1, msg_W[(m + 1) * 256 + k], a1);
            a2 = fmaf(w2, msg_W[(m + 2) * 256 + k], a2);
            a3 = fmaf(w3, msg_W[(m + 3) * 256 + k], a3);
            accb = fmaf(w0, msg_b[m + 0], accb);
            accb = fmaf(w1, msg_b[m + 1], accb);
            accb = fmaf(w2, msg_b[m + 2], accb);
            accb = fmaf(w3, msg_b[m + 3], accb);
        }
        w12b[j * 256 + k] = f2bf((a0 + a1) + (a2 + a3));
        if (k == 0) { bv[j] = accb; ucol[j] = upd_W[j * 257 + 256]; }
    }
}

// y = bf16(x @ W12^T) in PERMUTED layout (col' = w*64+lr*4+jt holds true
// col w*64+jt*16+lr). R19-verified schedule: per tile,
//   LDS-write(t) -> barrier (nothing in flight) -> issue loads(t+1)
//   -> ds_read+MFMA+store(t)
// so loads(t+1) stay in flight across the compute phase.
__global__ __launch_bounds__(256) void ygemm_kernel(
    const float* __restrict__ x, const unsigned short* __restrict__ w12b,
    unsigned short* __restrict__ y, int n_var, int ntiles) {

    __shared__ unsigned short sA[2][16 * 256];   // 2 x 8 KB swizzled bf16 A
    const int tid = threadIdx.x, w = tid >> 6, lane = tid & 63;
    const int lr = lane & 15, lg = lane >> 4;

    short8 bfr[4][8];
#pragma unroll
    for (int jt = 0; jt < 4; ++jt)
#pragma unroll
        for (int ks = 0; ks < 8; ++ks)
            bfr[jt][ks] = *(const short8*)(w12b + (w * 64 + jt * 16 + lr) * HD + lg * 8 + ks * 32);

    const int srow = tid >> 4, scol = (tid & 15) * 16;   // stage: 16 thr/row
    const int b0 = (srow * 512 + scol * 2) ^ ((srow & 7) << 4);
    const int b1 = (srow * 512 + scol * 2 + 16) ^ ((srow & 7) << 4);

    int rt = blockIdx.x;
    float4 u0, u1, u2, u3;
    if (rt < ntiles) {
        int arc = min(rt * 16 + srow, n_var - 1);
        const float* gp = x + (long)arc * HD + scol;
        u0 = *(const float4*)(gp);
        u1 = *(const float4*)(gp + 4);
        u2 = *(const float4*)(gp + 8);
        u3 = *(const float4*)(gp + 12);
    }

    int buf = 0;
#pragma unroll 1
    for (; rt < ntiles; ) {
        int r0 = rt * 16;
        // ---- write the prefetched (in-register) tile to LDS ----
        *(short8*)((char*)&sA[buf][0] + b0) = cvt8(u0, u1);
        *(short8*)((char*)&sA[buf][0] + b1) = cvt8(u2, u3);

        // ---- barrier BEFORE issuing next loads (nothing in flight) ----
        __syncthreads();

        // ---- issue next tile's global loads (in flight across compute) ----
        int nrt = rt + gridDim.x;
        {
            int prt = min(nrt, ntiles - 1);
            int arc = min(prt * 16 + srow, n_var - 1);
            const float* gp = x + (long)arc * HD + scol;
            u0 = *(const float4*)(gp);
            u1 = *(const float4*)(gp + 4);
            u2 = *(const float4*)(gp + 8);
            u3 = *(const float4*)(gp + 12);
        }

        short8 af[8];
#pragma unroll
        for (int ks = 0; ks < 8; ++ks) {
            int byte = (lr * 512 + (ks * 32 + lg * 8) * 2) ^ ((lr & 7) << 4);
            af[ks] = *(const short8*)((char*)&sA[buf][0] + byte);
        }

        f32x4 acc[4] = {{0.f,0.f,0.f,0.f},{0.f,0.f,0.f,0.f},{0.f,0.f,0.f,0.f},{0.f,0.f,0.f,0.f}};
#pragma unroll
        for (int ks = 0; ks < 8; ++ks)
#pragma unroll
            for (int jt = 0; jt < 4; ++jt)
                acc[jt] = __builtin_amdgcn_mfma_f32_16x16x32_bf16(af[ks], bfr[jt][ks], acc[jt], 0, 0, 0);

        // ---- direct permuted store: lane packs its 4 jt-values per row ----
#pragma unroll
        for (int q = 0; q < 4; ++q) {
            int grow = r0 + lg * 4 + q;
            if (grow < n_var) {
                s16x4 o;
#pragma unroll
                for (int jt = 0; jt < 4; ++jt) o[jt] = (short)f2bf(acc[jt][q]);
                *(s16x4*)(y + (long)grow * HD + w * 64 + lr * 4) = o;
            }
        }
        buf ^= 1;
        rt = nrt;
    }
}

// Gather + epilogue. y is in permuted layout: component jt of the 8B read
// at col' = lane*4 corresponds to TRUE col c_jt = (lane>>4)*64 + jt*16 +
// (lane&15). Per-col params are loaded at c_jt; LN sum is col-order
// agnostic; out stores go to the true cols.
__global__ __launch_bounds__(256) void gatherln_kernel(
    const unsigned short* __restrict__ y, const int* __restrict__ counts,
    const int* __restrict__ eidx, const float* __restrict__ clue,
    const float* __restrict__ bv, const float* __restrict__ ucol,
    const float* __restrict__ upd_b,
    const float* __restrict__ ln_w, const float* __restrict__ ln_b,
    float* __restrict__ out, int num_con) {
    int row  = blockIdx.x * 4 + (threadIdx.x >> 6);
    int lane = threadIdx.x & 63;
    if (row >= num_con) return;
    int cnt = counts[row];
    int cgo = min(cnt, CAP);
    int sid = (lane < cgo) ? eidx[row * CAP + lane] : 0;
    float a0 = 0.f, a1 = 0.f, a2 = 0.f, a3 = 0.f;
#pragma unroll 1
    for (int i = 0; i < cgo; i += 8) {
        int s[8];
#pragma unroll
        for (int u = 0; u < 8; ++u) s[u] = __shfl(sid, i + u, 64);
        s16x4 v[8];
#pragma unroll
        for (int u = 0; u < 8; ++u)
            v[u] = *(const s16x4*)(y + (long)s[u] * HD + lane * 4);
#pragma unroll
        for (int u = 0; u < 8; ++u) {
            float wg = (i + u < cgo) ? 1.f : 0.f;
            a0 = fmaf(bf2f((unsigned short)v[u][0]), wg, a0);
            a1 = fmaf(bf2f((unsigned short)v[u][1]), wg, a1);
            a2 = fmaf(bf2f((unsigned short)v[u][2]), wg, a2);
            a3 = fmaf(bf2f((unsigned short)v[u][3]), wg, a3);
        }
    }
    // true cols for components 0..3
    int c0 = ((lane >> 4) << 6) + (lane & 15);   // + jt*16
    float sc = 1.0f / ((float)cnt + DEG_EPS);
    float tc = (float)cnt * sc;
    float cl = clue[row];
    float z[4] = {a0, a1, a2, a3};
    float s = 0.f, s2 = 0.f;
#pragma unroll
    for (int jt = 0; jt < 4; ++jt) {
        int c = c0 + jt * 16;
        float zz = fmaxf(z[jt] * sc + tc * bv[c] + cl * ucol[c] + upd_b[c], 0.0f);
        z[jt] = zz;
        s += zz; s2 += zz * zz;
    }
#pragma unroll
    for (int m = 1; m < 64; m <<= 1) {
        s  += __shfl_xor(s,  m, 64);
        s2 += __shfl_xor(s2, m, 64);
    }
    float mu = s * (1.0f / HD);
    float var = s2 * (1.0f / HD) - mu * mu;
    float rs = rsqrtf(var + LN_EPS);
    float* gp = out + (long)row * HD;
#pragma unroll
    for (int jt = 0; jt < 4; ++jt) {
        int c = c0 + jt * 16;
        gp[c] = (z[jt] - mu) * rs * ln_w[c] + ln_b[c];
    }
}

extern "C" void kernel_launch(void* const* d_in, const int* in_sizes, int n_in,
                              void* d_out, int out_size, void* d_ws, size_t ws_size,
                              hipStream_t stream) {
    const float* x_var = (const float*)d_in[0];
    const int*   src   = (const int*)d_in[1];
    const int*   dst   = (const int*)d_in[2];
    const float* clue  = (const float*)d_in[3];
    // d_in[4] = num_con scalar (derived from out_size instead)
    const float* msg_W = (const float*)d_in[5];
    const float* msg_b = (const float*)d_in[6];
    const float* upd_W = (const float*)d_in[7];
    const float* upd_b = (const float*)d_in[8];
    const float* ln_w  = (const float*)d_in[9];
    const float* ln_b  = (const float*)d_in[10];

    int E = in_sizes[1];
    long n_x = in_sizes[0];
    int n_var = (int)(n_x / HD);
    int num_con = out_size / HD;
    int ntiles_v = (n_var + 15) / 16;

    char* ws = (char*)d_ws;
    int* counts = (int*)ws;                               // num_con ints
    int* eidx   = (int*)(ws + (((size_t)num_con * 4 + 255) & ~(size_t)255));
    char* after = (char*)(eidx + (size_t)num_con * CAP);  // num_con*CAP ints
    size_t yoff = ((size_t)(after - ws) + 255) & ~(size_t)255;
    unsigned short* yv = (unsigned short*)(ws + yoff);    // n_var*256 bf16 (permuted)
    size_t woff = (yoff + (size_t)n_var * HD * 2 + 255) & ~(size_t)255;
    unsigned short* w12b = (unsigned short*)(ws + woff);  // 256*256 bf16
    float* bvp  = (float*)(w12b + 256 * 256);             // 256 fp32
    float* ucol = bvp + 256;                              // 256 fp32

    zero_kernel<<<(num_con + 1023) / 1024, 256, 0, stream>>>(counts, num_con);

    int FB = (E + 255) / 256;
    fillw12_kernel<<<FB + 256, 256, 0, stream>>>(
        src, dst, counts, eidx, E, FB,
        msg_W, msg_b, upd_W, w12b, bvp, ucol);

    ygemm_kernel<<<1024, 256, 0, stream>>>(x_var, w12b, yv, n_var, ntiles_v);

    gatherln_kernel<<<(num_con + 3) / 4, 256, 0, stream>>>(
        yv, counts, eidx, clue, bvp, ucol, upd_b, ln_w, ln_b,
        (float*)d_out, num_con);
}